// Round 11
// baseline (227.156 us; speedup 1.0000x reference)
//
#include <hip/hip_runtime.h>
#include <hip/hip_cooperative_groups.h>
#include <hip/hip_bf16.h>
#include <stdint.h>

namespace cg = cooperative_groups;

// out[i][j] = dot(x[i], y[j]) / max(|x[i]|*|y[j]|, 1e-8) / 0.05
// x,y: [4096,1024] f32; out: [4096,4096] f32
// SINGLE cooperative dispatch: phase 1 converts f32->bf16 panels + row norms
// into workspace (each row converted exactly once), grid.sync(), phase 2 runs
// the verified R8 GEMM (8-phase counted-vmcnt, 16x16x32, zero-conflict LDS).
#define MDIM 4096
#define NDIM 4096
#define KDIM 1024
#define TEMP_INV 20.0f

#define BM 256
#define BN 256
#define BK 64
#define NT (KDIM / BK)       // 16 K-tiles -> 8 double-tile iterations
#define ABUF_E (BM * BK)     // 16384 elems = 32 KB (A region; B same)
#define BUF_E (2 * ABUF_E)   // 64 KB per buffer; 2 buffers = 128 KB

typedef __bf16 bf16x8 __attribute__((ext_vector_type(8)));
typedef float f32x4 __attribute__((ext_vector_type(4)));

typedef __attribute__((address_space(3))) void lds_void_t;
typedef __attribute__((address_space(1))) void glb_void_t;

__device__ __forceinline__ void async_copy16(const void* g, void* l) {
    __builtin_amdgcn_global_load_lds((glb_void_t*)(uintptr_t)g,
                                     (lds_void_t*)(uint32_t)(uintptr_t)l,
                                     16, 0, 0);
}

__device__ __forceinline__ unsigned short f32_to_bf16_rne(float f) {
    union { float f; uint32_t u; } v;
    v.f = f;
    uint32_t u = v.u;
    return (unsigned short)((u + 0x7FFFu + ((u >> 16) & 1u)) >> 16);
}

// ---- staging/wait macros (verified R7/R8 ladder) ----
#define STA(buf, v, seg) async_copy16(gAsrc + (v) * BK + (size_t)((seg) * 64) * KDIM, \
                                      (buf) + (seg) * 4096 + tid * 8)
#define STB(buf, v, seg) async_copy16(gBsrc + (v) * BK + (size_t)((seg) * 64) * KDIM, \
                                      (buf) + ABUF_E + (seg) * 4096 + tid * 8)
#define PH_SYNC() do { __builtin_amdgcn_s_barrier();                         \
                       asm volatile("s_waitcnt lgkmcnt(0)" ::: "memory");    \
                       __builtin_amdgcn_sched_barrier(0); } while (0)

#define MFMA16(MB, NB)                                                        \
    do { __builtin_amdgcn_s_setprio(1);                                       \
         _Pragma("unroll") for (int kh = 0; kh < 2; ++kh)                     \
         _Pragma("unroll") for (int ni = 0; ni < 2; ++ni)                     \
         _Pragma("unroll") for (int mi = 0; mi < 4; ++mi)                     \
             acc[(MB) + mi][(NB) + ni] = __builtin_amdgcn_mfma_f32_16x16x32_bf16( \
                 aF[mi][kh], bF[(NB) + ni][kh], acc[(MB) + mi][(NB) + ni], 0, 0, 0); \
         __builtin_amdgcn_s_setprio(0); } while (0)

#define RD_A(bufp)                                                            \
    _Pragma("unroll") for (int mi = 0; mi < 4; ++mi) {                        \
        aF[mi][0] = *(const bf16x8*)((bufp) + 1024 * mi + cp0);               \
        aF[mi][1] = *(const bf16x8*)((bufp) + 1024 * mi + cp1);               \
    }
#define RD_B(bufp, NB)                                                        \
    _Pragma("unroll") for (int ni = 0; ni < 2; ++ni) {                        \
        bF[(NB) + ni][0] = *(const bf16x8*)((bufp) + 1024 * ((NB) + ni) + cp0); \
        bF[(NB) + ni][1] = *(const bf16x8*)((bufp) + 1024 * ((NB) + ni) + cp1); \
    }

template <bool LAST>
__device__ __forceinline__ void iter8(__bf16* buf0, __bf16* buf1,
                                      const unsigned short* gAsrc,
                                      const unsigned short* gBsrc, int u,
                                      int aRow, int bRow, int cp0, int cp1,
                                      int tid, f32x4 (&acc)[8][4]) {
    bf16x8 aF[4][2], bF[4][2];

    // ======== K-tile u (buf0) ========
    RD_A(buf0 + aRow)
    RD_B(buf0 + bRow, 0)
    STA(buf1, u + 1, 1); STA(buf1, u + 1, 3);
    PH_SYNC();
    MFMA16(0, 0);
    __builtin_amdgcn_s_barrier();

    RD_B(buf0 + bRow, 2)
    if constexpr (!LAST) { STA(buf0, u + 2, 0); STA(buf0, u + 2, 2); }
    PH_SYNC();
    MFMA16(0, 2);
    __builtin_amdgcn_s_barrier();

    RD_A(buf0 + aRow + 4096)
    if constexpr (!LAST) { STB(buf0, u + 2, 0); STB(buf0, u + 2, 1); }
    PH_SYNC();
    MFMA16(4, 0);
    __builtin_amdgcn_s_barrier();

    if constexpr (!LAST) { STB(buf0, u + 2, 2); STB(buf0, u + 2, 3); }
    MFMA16(4, 2);
    if constexpr (!LAST) asm volatile("s_waitcnt vmcnt(6)" ::: "memory");
    else                 asm volatile("s_waitcnt vmcnt(0)" ::: "memory");
    __builtin_amdgcn_sched_barrier(0);
    __builtin_amdgcn_s_barrier();

    // ======== K-tile u+1 (buf1) ========
    RD_A(buf1 + aRow)
    RD_B(buf1 + bRow, 0)
    if constexpr (!LAST) { STA(buf0, u + 2, 1); STA(buf0, u + 2, 3); }
    PH_SYNC();
    MFMA16(0, 0);
    __builtin_amdgcn_s_barrier();

    RD_B(buf1 + bRow, 2)
    if constexpr (!LAST) { STA(buf1, u + 3, 0); STA(buf1, u + 3, 2); }
    PH_SYNC();
    MFMA16(0, 2);
    __builtin_amdgcn_s_barrier();

    RD_A(buf1 + aRow + 4096)
    if constexpr (!LAST) { STB(buf1, u + 3, 0); STB(buf1, u + 3, 1); }
    PH_SYNC();
    MFMA16(4, 0);
    __builtin_amdgcn_s_barrier();

    if constexpr (!LAST) { STB(buf1, u + 3, 2); STB(buf1, u + 3, 3); }
    MFMA16(4, 2);
    if constexpr (!LAST) {
        asm volatile("s_waitcnt vmcnt(6)" ::: "memory");
        __builtin_amdgcn_sched_barrier(0);
        __builtin_amdgcn_s_barrier();
    }
}

// R8's verified GEMM body (256x256 tile, 8 waves 2Mx4N, wave tile 128x64).
__device__ __forceinline__ void gemm_body(const unsigned short* __restrict__ Xb,
                                          const unsigned short* __restrict__ Yb,
                                          const float* __restrict__ rnx,
                                          const float* __restrict__ rny,
                                          float* __restrict__ out, int lin) {
    __shared__ __bf16 lds[2 * BUF_E];  // 128 KB

    const int tid = threadIdx.x;

    // Rect XCD swizzle: lin&7 -> XCD; each XCD covers a 4bm x 8bn rectangle.
    const int x8 = lin & 7;
    const int ii = lin >> 3;  // 0..31 within XCD
    const int bm = 4 * (x8 >> 1) + (ii >> 3);
    const int bn = 8 * (x8 & 1) + (ii & 7);

    const int srow = tid >> 3;
    const int gch = (tid & 7) ^ (srow & 7);
    const unsigned short* gAsrc = Xb + (size_t)(bm * BM + srow) * KDIM + gch * 8;
    const unsigned short* gBsrc = Yb + (size_t)(bn * BN + srow) * KDIM + gch * 8;

    const int lane = tid & 63;
    const int wv = tid >> 6;
    const int wm = wv >> 2;   // 0..1 -> A rows wm*128..
    const int wn = wv & 3;    // 0..3 -> B rows wn*64..
    const int l15 = lane & 15;
    const int kb = lane >> 4;      // 0..3 k-block
    const int sw = lane & 7;       // swizzle xor term

    const int aRow = (wm * 128 + l15) * 64;            // + mi*1024 + cp
    const int bRow = ABUF_E + (wn * 64 + l15) * 64;    // + ni*1024 + cp
    const int cp0 = (kb ^ sw) * 8;                     // kh=0 chunk
    const int cp1 = ((4 + kb) ^ sw) * 8;               // kh=1 chunk

    f32x4 acc[8][4];
#pragma unroll
    for (int i = 0; i < 8; ++i)
#pragma unroll
        for (int j = 0; j < 4; ++j) acc[i][j] = (f32x4){};

    __bf16* buf0 = lds;
    __bf16* buf1 = lds + BUF_E;

    // prologue: tile 0 complete + tile 1's A02,B01,B23 (6 loads in flight)
    STA(buf0, 0, 0); STA(buf0, 0, 2);
    STB(buf0, 0, 0); STB(buf0, 0, 1); STB(buf0, 0, 2); STB(buf0, 0, 3);
    STA(buf0, 0, 1); STA(buf0, 0, 3);
    STA(buf1, 1, 0); STA(buf1, 1, 2);
    STB(buf1, 1, 0); STB(buf1, 1, 1); STB(buf1, 1, 2); STB(buf1, 1, 3);
    asm volatile("s_waitcnt vmcnt(6)" ::: "memory");
    __builtin_amdgcn_sched_barrier(0);
    __builtin_amdgcn_s_barrier();

#pragma unroll 1
    for (int i = 0; i < 7; ++i)
        iter8<false>(buf0, buf1, gAsrc, gBsrc, 2 * i, aRow, bRow, cp0, cp1, tid, acc);
    iter8<true>(buf0, buf1, gAsrc, gBsrc, 14, aRow, bRow, cp0, cp1, tid, acc);

    // Epilogue. C/D (16x16, m89/m91): col = lane&15, row = (lane>>4)*4 + reg.
    const int grbase = bm * BM + wm * 128 + kb * 4;
    const int gcbase = bn * BN + wn * 64 + l15;
    float sy[4];
#pragma unroll
    for (int ni = 0; ni < 4; ++ni) sy[ni] = rny[gcbase + ni * 16] * TEMP_INV;

#pragma unroll
    for (int mi = 0; mi < 8; ++mi) {
#pragma unroll
        for (int r = 0; r < 4; ++r) {
            const int grow = grbase + mi * 16 + r;
            const float rx = rnx[grow];
            float* orow = out + (size_t)grow * NDIM;
#pragma unroll
            for (int ni = 0; ni < 4; ++ni)
                orow[gcbase + ni * 16] = acc[mi][ni][r] * rx * sy[ni];
        }
    }
}

// Fused cooperative kernel: prep (each block: 16 x-rows + 16 y-rows, one
// conversion per row grid-wide) -> threadfence + grid.sync -> R8 GEMM.
__global__ __launch_bounds__(512, 2) void fused_kernel(const float* __restrict__ x,
                                                       const float* __restrict__ y,
                                                       unsigned short* __restrict__ Xb,
                                                       unsigned short* __restrict__ Yb,
                                                       float* __restrict__ rnx,
                                                       float* __restrict__ rny,
                                                       float* __restrict__ out) {
    const int tid = threadIdx.x;
    {
        const int wv8 = tid >> 6;          // 0..7
        const int lane = tid & 63;
        const float* sp = (wv8 & 4) ? y : x;
        unsigned short* dp = (wv8 & 4) ? Yb : Xb;
        float* rp = (wv8 & 4) ? rny : rnx;
        const int rbase = (int)blockIdx.x * 16 + (wv8 & 3) * 4;
#pragma unroll
        for (int rr = 0; rr < 4; ++rr) {
            const int row = rbase + rr;
            const float4* s4 = (const float4*)(sp + (size_t)row * KDIM);
            ushort4* d4 = (ushort4*)(dp + (size_t)row * KDIM);
            float ss = 0.0f;
#pragma unroll
            for (int it = 0; it < 4; ++it) {
                float4 v = s4[lane + it * 64];
                ss += v.x * v.x + v.y * v.y + v.z * v.z + v.w * v.w;
                ushort4 b;
                b.x = f32_to_bf16_rne(v.x);
                b.y = f32_to_bf16_rne(v.y);
                b.z = f32_to_bf16_rne(v.z);
                b.w = f32_to_bf16_rne(v.w);
                d4[lane + it * 64] = b;
            }
#pragma unroll
            for (int off = 32; off > 0; off >>= 1) ss += __shfl_down(ss, off);
            if (lane == 0) rp[row] = 1.0f / fmaxf(sqrtf(ss), 1e-8f);
        }
    }
    __threadfence();            // device-scope release (cross-XCD visibility)
    cg::this_grid().sync();     // all panels + norms ready, device-wide

    gemm_body(Xb, Yb, rnx, rny, out, (int)blockIdx.x);
}

extern "C" void kernel_launch(void* const* d_in, const int* in_sizes, int n_in,
                              void* d_out, int out_size, void* d_ws, size_t ws_size,
                              hipStream_t stream) {
    const float* x = (const float*)d_in[0];
    const float* y = (const float*)d_in[1];
    float* out = (float*)d_out;

    char* ws = (char*)d_ws;
    unsigned short* Xb = (unsigned short*)ws;                              // 8 MB
    unsigned short* Yb = (unsigned short*)(ws + (size_t)MDIM * KDIM * 2);  // 8 MB
    float* rnx = (float*)(ws + (size_t)(MDIM + NDIM) * KDIM * 2);
    float* rny = rnx + MDIM;

    void* args[] = {(void*)&x, (void*)&y, (void*)&Xb, (void*)&Yb,
                    (void*)&rnx, (void*)&rny, (void*)&out};
    hipLaunchCooperativeKernel(reinterpret_cast<void*>(fused_kernel),
                               dim3(256), dim3(512), args, 0, stream);
}

// Round 12
// 125.839 us; speedup vs baseline: 1.8051x; 1.8051x over previous
//
#include <hip/hip_runtime.h>
#include <hip/hip_bf16.h>
#include <stdint.h>

// out[i][j] = dot(x[i], y[j]) / max(|x[i]|*|y[j]|, 1e-8) / 0.05
// x,y: [4096,1024] f32; out: [4096,4096] f32
#define MDIM 4096
#define NDIM 4096
#define KDIM 1024
#define TEMP_INV 20.0f

#define BM 128
#define BN 256
#define BK 64
#define NT (KDIM / BK)     // 16 K-tiles -> 8 double-tile iterations
#define A_E (BM * BK)      // 8192 elems = 16 KB (A region)
#define B_E (BN * BK)      // 16384 elems = 32 KB (B region)
#define BUF_E (A_E + B_E)  // 24576 elems = 48 KB/buffer; 2 buffers = 96 KB LDS

typedef __bf16 bf16x8 __attribute__((ext_vector_type(8)));
typedef float f32x4 __attribute__((ext_vector_type(4)));

typedef __attribute__((address_space(3))) void lds_void_t;
typedef __attribute__((address_space(1))) void glb_void_t;

__device__ __forceinline__ void async_copy16(const void* g, void* l) {
    __builtin_amdgcn_global_load_lds((glb_void_t*)(uintptr_t)g,
                                     (lds_void_t*)(uint32_t)(uintptr_t)l,
                                     16, 0, 0);
}

__device__ __forceinline__ unsigned short f32_to_bf16_rne(float f) {
    union { float f; uint32_t u; } v;
    v.f = f;
    uint32_t u = v.u;
    return (unsigned short)((u + 0x7FFFu + ((u >> 16) & 1u)) >> 16);
}

// Wave-per-row prep: no LDS, no __syncthreads. Block = 4 waves = 4 rows.
__global__ __launch_bounds__(256) void prep_kernel(const float* __restrict__ x,
                                                   const float* __restrict__ y,
                                                   unsigned short* __restrict__ xb,
                                                   unsigned short* __restrict__ yb,
                                                   float* __restrict__ rnx,
                                                   float* __restrict__ rny) {
    const int wv = threadIdx.x >> 6;
    const int lane = threadIdx.x & 63;
    const int row = blockIdx.x * 4 + wv;
    const float* src = blockIdx.y ? y : x;
    unsigned short* dst = blockIdx.y ? yb : xb;
    float* rn = blockIdx.y ? rny : rnx;

    const float4* s4 = (const float4*)(src + (size_t)row * KDIM);
    ushort4* d4 = (ushort4*)(dst + (size_t)row * KDIM);

    float ss = 0.0f;
#pragma unroll
    for (int it = 0; it < 4; ++it) {
        float4 v = s4[lane + it * 64];
        ss += v.x * v.x + v.y * v.y + v.z * v.z + v.w * v.w;
        ushort4 b;
        b.x = f32_to_bf16_rne(v.x);
        b.y = f32_to_bf16_rne(v.y);
        b.z = f32_to_bf16_rne(v.z);
        b.w = f32_to_bf16_rne(v.w);
        d4[lane + it * 64] = b;
    }
#pragma unroll
    for (int off = 32; off > 0; off >>= 1) ss += __shfl_down(ss, off);
    if (lane == 0) rn[row] = 1.0f / fmaxf(sqrtf(ss), 1e-8f);
}

// ---- 4-phase double-K-tile iteration (derived-wait ladder for 6 loads/tile).
// Iteration: tile u (buf0) = ph1,ph2; tile u+1 (buf1) = ph3,ph4.
// Stage slots (target region provably dead >=1 barrier earlier):
//   ph1: B23(u+1)->buf1 (2)   [dead since prev ph4-end]
//   ph2: A+B01(u+2)->buf0 (4) [A,B01 die at ph1-end]
//   ph3: B23(u+2)->buf0 (2)   [B23 dies at ph2-end]
//   ph4: A+B01(u+3)->buf1 (4) [die at ph3-end]
// Boundary vmcnt(4) at ph2-end and ph4-end: retires the 6 oldest (next tile's
// loads) and leaves the newest 4 in flight across the barrier. Depth <= 10.
#define STA(buf, v, seg) async_copy16(gAsrc + (v) * BK + (size_t)((seg) * 64) * KDIM, \
                                      (buf) + (seg) * 4096 + tid * 8)
#define STB(buf, v, seg) async_copy16(gBsrc + (v) * BK + (size_t)((seg) * 64) * KDIM, \
                                      (buf) + A_E + (seg) * 4096 + tid * 8)
#define PH_SYNC() do { __builtin_amdgcn_s_barrier();                         \
                       asm volatile("s_waitcnt lgkmcnt(0)" ::: "memory");    \
                       __builtin_amdgcn_sched_barrier(0); } while (0)

#define MFMA16(NB)                                                            \
    do { __builtin_amdgcn_s_setprio(1);                                       \
         _Pragma("unroll") for (int kh = 0; kh < 2; ++kh)                     \
         _Pragma("unroll") for (int ni = 0; ni < 2; ++ni)                     \
         _Pragma("unroll") for (int mi = 0; mi < 4; ++mi)                     \
             acc[mi][(NB) + ni] = __builtin_amdgcn_mfma_f32_16x16x32_bf16(    \
                 aF[mi][kh], bF[ni][kh], acc[mi][(NB) + ni], 0, 0, 0);        \
         __builtin_amdgcn_s_setprio(0); } while (0)

#define RD_A(bufp)                                                            \
    _Pragma("unroll") for (int mi = 0; mi < 4; ++mi) {                        \
        aF[mi][0] = *(const bf16x8*)((bufp) + 1024 * mi + cp0);               \
        aF[mi][1] = *(const bf16x8*)((bufp) + 1024 * mi + cp1);               \
    }
#define RD_B2(bufp, NB)                                                       \
    _Pragma("unroll") for (int ni = 0; ni < 2; ++ni) {                        \
        bF[ni][0] = *(const bf16x8*)((bufp) + 1024 * ((NB) + ni) + cp0);      \
        bF[ni][1] = *(const bf16x8*)((bufp) + 1024 * ((NB) + ni) + cp1);      \
    }

template <bool LAST>
__device__ __forceinline__ void iter4(__bf16* buf0, __bf16* buf1,
                                      const unsigned short* gAsrc,
                                      const unsigned short* gBsrc, int u,
                                      int aRow, int bRow, int cp0, int cp1,
                                      int tid, f32x4 (&acc)[4][4]) {
    bf16x8 aF[4][2], bF[2][2];

    // ---- ph1 (tile u, buf0): read A all + B ni0-1; stage B23(u+1)->buf1
    RD_A(buf0 + aRow)
    RD_B2(buf0 + bRow, 0)
    STB(buf1, u + 1, 2); STB(buf1, u + 1, 3);
    PH_SYNC();
    MFMA16(0);
    __builtin_amdgcn_s_barrier();

    // ---- ph2: read B ni2-3; stage A+B01(u+2)->buf0; boundary vmcnt
    RD_B2(buf0 + bRow, 2)
    if constexpr (!LAST) { STA(buf0, u + 2, 0); STA(buf0, u + 2, 1);
                           STB(buf0, u + 2, 0); STB(buf0, u + 2, 1); }
    PH_SYNC();
    MFMA16(2);
    if constexpr (!LAST) asm volatile("s_waitcnt vmcnt(4)" ::: "memory");
    else                 asm volatile("s_waitcnt vmcnt(0)" ::: "memory");
    __builtin_amdgcn_sched_barrier(0);
    __builtin_amdgcn_s_barrier();

    // ---- ph3 (tile u+1, buf1): read A all + B ni0-1; stage B23(u+2)->buf0
    RD_A(buf1 + aRow)
    RD_B2(buf1 + bRow, 0)
    if constexpr (!LAST) { STB(buf0, u + 2, 2); STB(buf0, u + 2, 3); }
    PH_SYNC();
    MFMA16(0);
    __builtin_amdgcn_s_barrier();

    // ---- ph4: read B ni2-3; stage A+B01(u+3)->buf1; boundary vmcnt
    RD_B2(buf1 + bRow, 2)
    if constexpr (!LAST) { STA(buf1, u + 3, 0); STA(buf1, u + 3, 1);
                           STB(buf1, u + 3, 0); STB(buf1, u + 3, 1); }
    PH_SYNC();
    MFMA16(2);
    if constexpr (!LAST) {
        asm volatile("s_waitcnt vmcnt(4)" ::: "memory");
        __builtin_amdgcn_sched_barrier(0);
        __builtin_amdgcn_s_barrier();
    }
}

// 128x256 tile, BK=64, 512 threads / 8 waves (2M x 4N), wave tile 64x64,
// 16x16x32 MFMA (acc 4x4 f32x4 = 64 regs), 2 LDS buffers (96 KB) -> grid 512
// = 2 launched blocks/CU: block k's HBM store drain overlaps block k+256's
// compute on the same CU; straggler quantum halves. 8-phase-family counted-
// vmcnt schedule, zero-conflict chunk-XOR swizzle, verified C/D layout.
__global__ __launch_bounds__(512, 2) void gemm_cos_kernel(const unsigned short* __restrict__ Xb,
                                                          const unsigned short* __restrict__ Yb,
                                                          const float* __restrict__ rnx,
                                                          const float* __restrict__ rny,
                                                          float* __restrict__ out) {
    __shared__ __bf16 lds[2 * BUF_E];  // 96 KB

    const int tid = threadIdx.x;

    // Rect XCD swizzle: 512 blocks = 8 XCD x 64; each XCD gets an 8bm x 8bn
    // rectangle (L2 footprint: 8 A-panels (2 MB) + 8 B-panels (4 MB) = 6 MB).
    const int lin = (int)(blockIdx.y * gridDim.x + blockIdx.x);
    const int x8 = lin & 7;
    const int ii = lin >> 3;  // 0..63 within XCD
    const int bm = (x8 & 3) * 8 + (ii >> 3);   // 0..31
    const int bn = (x8 >> 2) * 8 + (ii & 7);   // 0..15

    // Staging: thread t covers seg-row (t>>3) (0..63), chunk slot (t&7);
    // fetches global chunk (t&7)^(srow&7) so LDS slot c' holds chunk c'^(row&7).
    const int srow = tid >> 3;
    const int gch = (tid & 7) ^ (srow & 7);
    const unsigned short* gAsrc = Xb + (size_t)(bm * BM + srow) * KDIM + gch * 8;
    const unsigned short* gBsrc = Yb + (size_t)(bn * BN + srow) * KDIM + gch * 8;

    const int lane = tid & 63;
    const int wv = tid >> 6;
    const int wm = wv >> 2;   // 0..1 -> A rows wm*64..
    const int wn = wv & 3;    // 0..3 -> B rows wn*64..
    const int l15 = lane & 15;
    const int kb = lane >> 4;      // 0..3 k-block
    const int sw = lane & 7;       // swizzle xor term (row&7 of the frag row)

    const int aRow = (wm * 64 + l15) * 64;          // + mi*1024 + cp
    const int bRow = A_E + (wn * 64 + l15) * 64;    // + ni*1024 + cp
    const int cp0 = (kb ^ sw) * 8;                  // kh=0 chunk
    const int cp1 = ((4 + kb) ^ sw) * 8;            // kh=1 chunk

    f32x4 acc[4][4];
#pragma unroll
    for (int i = 0; i < 4; ++i)
#pragma unroll
        for (int j = 0; j < 4; ++j) acc[i][j] = (f32x4){};

    __bf16* buf0 = lds;
    __bf16* buf1 = lds + BUF_E;

    // ---- prologue: tile 0 complete (6 loads) + tile 1's A,B01 (4 loads)
    STA(buf0, 0, 0); STA(buf0, 0, 1);
    STB(buf0, 0, 0); STB(buf0, 0, 1); STB(buf0, 0, 2); STB(buf0, 0, 3);
    STA(buf1, 1, 0); STA(buf1, 1, 1);
    STB(buf1, 1, 0); STB(buf1, 1, 1);
    asm volatile("s_waitcnt vmcnt(4)" ::: "memory");  // tile 0 landed; 4 in flight
    __builtin_amdgcn_sched_barrier(0);
    __builtin_amdgcn_s_barrier();

    // ---- main: 7 full iterations + 1 last (NT=16 tiles)
#pragma unroll 1
    for (int i = 0; i < 7; ++i)
        iter4<false>(buf0, buf1, gAsrc, gBsrc, 2 * i, aRow, bRow, cp0, cp1, tid, acc);
    iter4<true>(buf0, buf1, gAsrc, gBsrc, 14, aRow, bRow, cp0, cp1, tid, acc);

    // Epilogue. C/D (16x16, m89/m91): col = lane&15, row = (lane>>4)*4 + reg.
    const int grbase = bm * BM + wm * 64 + kb * 4;
    const int gcbase = bn * BN + wn * 64 + l15;
    float sy[4];
#pragma unroll
    for (int ni = 0; ni < 4; ++ni) sy[ni] = rny[gcbase + ni * 16] * TEMP_INV;

#pragma unroll
    for (int mi = 0; mi < 4; ++mi) {
#pragma unroll
        for (int r = 0; r < 4; ++r) {
            const int grow = grbase + mi * 16 + r;
            const float rx = rnx[grow];
            float* orow = out + (size_t)grow * NDIM;
#pragma unroll
            for (int ni = 0; ni < 4; ++ni)
                orow[gcbase + ni * 16] = acc[mi][ni][r] * rx * sy[ni];
        }
    }
}

extern "C" void kernel_launch(void* const* d_in, const int* in_sizes, int n_in,
                              void* d_out, int out_size, void* d_ws, size_t ws_size,
                              hipStream_t stream) {
    const float* x = (const float*)d_in[0];
    const float* y = (const float*)d_in[1];
    float* out = (float*)d_out;

    char* ws = (char*)d_ws;
    unsigned short* Xb = (unsigned short*)ws;                              // 8 MB
    unsigned short* Yb = (unsigned short*)(ws + (size_t)MDIM * KDIM * 2);  // 8 MB
    float* rnx = (float*)(ws + (size_t)(MDIM + NDIM) * KDIM * 2);
    float* rny = rnx + MDIM;

    prep_kernel<<<dim3(MDIM / 4, 2), 256, 0, stream>>>(x, y, Xb, Yb, rnx, rny);
    gemm_cos_kernel<<<dim3(NDIM / BN, MDIM / BM), 512, 0, stream>>>(Xb, Yb, rnx, rny, out);
}

// Round 13
// 123.218 us; speedup vs baseline: 1.8435x; 1.0213x over previous
//
#include <hip/hip_runtime.h>
#include <hip/hip_bf16.h>
#include <stdint.h>

// out[i][j] = dot(x[i], y[j]) / max(|x[i]|*|y[j]|, 1e-8) / 0.05
// x,y: [4096,1024] f32; out: [4096,4096] f32
#define MDIM 4096
#define NDIM 4096
#define KDIM 1024
#define TEMP_INV 20.0f

#define BM 256
#define BN 256
#define BK 64
#define NT (KDIM / BK)       // 16 K-tiles -> 8 double-tile iterations
#define ABUF_E (BM * BK)     // 16384 elems = 32 KB (A region; B same)
#define BUF_E (2 * ABUF_E)   // 64 KB per buffer; 2 buffers = 128 KB

typedef __bf16 bf16x8 __attribute__((ext_vector_type(8)));
typedef float f32x4 __attribute__((ext_vector_type(4)));

typedef __attribute__((address_space(3))) void lds_void_t;
typedef __attribute__((address_space(1))) void glb_void_t;

__device__ __forceinline__ void async_copy16(const void* g, void* l) {
    __builtin_amdgcn_global_load_lds((glb_void_t*)(uintptr_t)g,
                                     (lds_void_t*)(uint32_t)(uintptr_t)l,
                                     16, 0, 0);
}

__device__ __forceinline__ unsigned short f32_to_bf16_rne(float f) {
    union { float f; uint32_t u; } v;
    v.f = f;
    uint32_t u = v.u;
    return (unsigned short)((u + 0x7FFFu + ((u >> 16) & 1u)) >> 16);
}

// Wave-per-row prep: no LDS, no __syncthreads. Block = 4 waves = 4 rows.
__global__ __launch_bounds__(256) void prep_kernel(const float* __restrict__ x,
                                                   const float* __restrict__ y,
                                                   unsigned short* __restrict__ xb,
                                                   unsigned short* __restrict__ yb,
                                                   float* __restrict__ rnx,
                                                   float* __restrict__ rny) {
    const int wv = threadIdx.x >> 6;
    const int lane = threadIdx.x & 63;
    const int row = blockIdx.x * 4 + wv;
    const float* src = blockIdx.y ? y : x;
    unsigned short* dst = blockIdx.y ? yb : xb;
    float* rn = blockIdx.y ? rny : rnx;

    const float4* s4 = (const float4*)(src + (size_t)row * KDIM);
    ushort4* d4 = (ushort4*)(dst + (size_t)row * KDIM);

    float ss = 0.0f;
#pragma unroll
    for (int it = 0; it < 4; ++it) {
        float4 v = s4[lane + it * 64];
        ss += v.x * v.x + v.y * v.y + v.z * v.z + v.w * v.w;
        ushort4 b;
        b.x = f32_to_bf16_rne(v.x);
        b.y = f32_to_bf16_rne(v.y);
        b.z = f32_to_bf16_rne(v.z);
        b.w = f32_to_bf16_rne(v.w);
        d4[lane + it * 64] = b;
    }
#pragma unroll
    for (int off = 32; off > 0; off >>= 1) ss += __shfl_down(ss, off);
    if (lane == 0) rn[row] = 1.0f / fmaxf(sqrtf(ss), 1e-8f);
}

// ---- 8-phase double-K-tile iteration, 16x16x32 MFMA (verified R7/R8 ladder).
//   ph1: A13(u+1)->buf1   ph2: A02(u+2)->buf0  ph3: B01(u+2)->buf0
//   ph4: B23(u+2)->buf0   ph5: A13(u+2)->buf0  ph6: A02(u+3)->buf1
//   ph7: B01(u+3)->buf1   ph8: B23(u+3)->buf1
// vmcnt(6) at ph4/ph8 only; in-flight depth reaches 14 and each boundary
// retires exactly the loads the next phase-group reads.
// Fragments (16x16x32, verified m89/m91): A/B lane&15 = row(col), k-chunk =
// (lane>>4)*8; C/D col = lane&15, row = (lane>>4)*4 + reg.
#define STA(buf, v, seg) async_copy16(gAsrc + (v) * BK + (size_t)((seg) * 64) * KDIM, \
                                      (buf) + (seg) * 4096 + tid * 8)
#define STB(buf, v, seg) async_copy16(gBsrc + (v) * BK + (size_t)((seg) * 64) * KDIM, \
                                      (buf) + ABUF_E + (seg) * 4096 + tid * 8)
#define PH_SYNC() do { __builtin_amdgcn_s_barrier();                         \
                       asm volatile("s_waitcnt lgkmcnt(0)" ::: "memory");    \
                       __builtin_amdgcn_sched_barrier(0); } while (0)

// 16-MFMA cluster: mi-range [MB, MB+4) x ni-range [NB, NB+2) x kh 0,1.
#define MFMA16(MB, NB)                                                        \
    do { __builtin_amdgcn_s_setprio(1);                                       \
         _Pragma("unroll") for (int kh = 0; kh < 2; ++kh)                     \
         _Pragma("unroll") for (int ni = 0; ni < 2; ++ni)                     \
         _Pragma("unroll") for (int mi = 0; mi < 4; ++mi)                     \
             acc[(MB) + mi][(NB) + ni] = __builtin_amdgcn_mfma_f32_16x16x32_bf16( \
                 aF[mi][kh], bF[(NB) + ni][kh], acc[(MB) + mi][(NB) + ni], 0, 0, 0); \
         __builtin_amdgcn_s_setprio(0); } while (0)

#define RD_A(bufp)                                                            \
    _Pragma("unroll") for (int mi = 0; mi < 4; ++mi) {                        \
        aF[mi][0] = *(const bf16x8*)((bufp) + 1024 * mi + cp0);               \
        aF[mi][1] = *(const bf16x8*)((bufp) + 1024 * mi + cp1);               \
    }
#define RD_B(bufp, NB)                                                        \
    _Pragma("unroll") for (int ni = 0; ni < 2; ++ni) {                        \
        bF[(NB) + ni][0] = *(const bf16x8*)((bufp) + 1024 * ((NB) + ni) + cp0); \
        bF[(NB) + ni][1] = *(const bf16x8*)((bufp) + 1024 * ((NB) + ni) + cp1); \
    }

template <bool LAST>
__device__ __forceinline__ void iter8(__bf16* buf0, __bf16* buf1,
                                      const unsigned short* gAsrc,
                                      const unsigned short* gBsrc, int u,
                                      int aRow, int bRow, int cp0, int cp1,
                                      int tid, f32x4 (&acc)[8][4]) {
    bf16x8 aF[4][2], bF[4][2];

    // ======== K-tile u (buf0) ========
    RD_A(buf0 + aRow)
    RD_B(buf0 + bRow, 0)
    STA(buf1, u + 1, 1); STA(buf1, u + 1, 3);
    PH_SYNC();
    MFMA16(0, 0);
    __builtin_amdgcn_s_barrier();

    RD_B(buf0 + bRow, 2)
    if constexpr (!LAST) { STA(buf0, u + 2, 0); STA(buf0, u + 2, 2); }
    PH_SYNC();
    MFMA16(0, 2);
    __builtin_amdgcn_s_barrier();

    RD_A(buf0 + aRow + 4096)
    if constexpr (!LAST) { STB(buf0, u + 2, 0); STB(buf0, u + 2, 1); }
    PH_SYNC();
    MFMA16(4, 0);
    __builtin_amdgcn_s_barrier();

    if constexpr (!LAST) { STB(buf0, u + 2, 2); STB(buf0, u + 2, 3); }
    MFMA16(4, 2);
    if constexpr (!LAST) asm volatile("s_waitcnt vmcnt(6)" ::: "memory");
    else                 asm volatile("s_waitcnt vmcnt(0)" ::: "memory");
    __builtin_amdgcn_sched_barrier(0);
    __builtin_amdgcn_s_barrier();

    // ======== K-tile u+1 (buf1) ========
    RD_A(buf1 + aRow)
    RD_B(buf1 + bRow, 0)
    if constexpr (!LAST) { STA(buf0, u + 2, 1); STA(buf0, u + 2, 3); }
    PH_SYNC();
    MFMA16(0, 0);
    __builtin_amdgcn_s_barrier();

    RD_B(buf1 + bRow, 2)
    if constexpr (!LAST) { STA(buf1, u + 3, 0); STA(buf1, u + 3, 2); }
    PH_SYNC();
    MFMA16(0, 2);
    __builtin_amdgcn_s_barrier();

    RD_A(buf1 + aRow + 4096)
    if constexpr (!LAST) { STB(buf1, u + 3, 0); STB(buf1, u + 3, 1); }
    PH_SYNC();
    MFMA16(4, 0);
    __builtin_amdgcn_s_barrier();

    if constexpr (!LAST) { STB(buf1, u + 3, 2); STB(buf1, u + 3, 3); }
    MFMA16(4, 2);
    if constexpr (!LAST) {
        asm volatile("s_waitcnt vmcnt(6)" ::: "memory");
        __builtin_amdgcn_sched_barrier(0);
        __builtin_amdgcn_s_barrier();
    }
}

// 256x256 tile, BK=64, 512 threads / 8 waves (2M x 4N), wave tile 128x64,
// 16x16x32 MFMA (acc 8x4 f32x4 = 128 regs/wave), 2 LDS buffers (128 KB),
// 8-phase counted-vmcnt schedule. Chunk-XOR LDS swizzle (conflict-free for
// the 16x16 lane pattern — measured SQ_LDS_BANK_CONFLICT = 0, R8).
__global__ __launch_bounds__(512, 2) void gemm_cos_kernel(const unsigned short* __restrict__ Xb,
                                                          const unsigned short* __restrict__ Yb,
                                                          const float* __restrict__ rnx,
                                                          const float* __restrict__ rny,
                                                          float* __restrict__ out) {
    __shared__ __bf16 lds[2 * BUF_E];  // 128 KB

    const int tid = threadIdx.x;

    // Rect XCD swizzle: lin&7 -> XCD; each XCD covers a 4bm x 8bn rectangle
    // (L2 footprint 4 A-panels + 8 B-panels = 6 MB; measured FETCH 24.7 MB).
    const int lin = (int)(blockIdx.y * gridDim.x + blockIdx.x);
    const int x8 = lin & 7;
    const int ii = lin >> 3;  // 0..31 within XCD
    const int bm = 4 * (x8 >> 1) + (ii >> 3);
    const int bn = 8 * (x8 & 1) + (ii & 7);

    // Staging: thread t covers seg-row (t>>3) (0..63), chunk slot (t&7);
    // fetches global chunk (t&7)^(srow&7) so LDS slot c' holds chunk c'^(row&7).
    const int srow = tid >> 3;
    const int gch = (tid & 7) ^ (srow & 7);
    const unsigned short* gAsrc = Xb + (size_t)(bm * BM + srow) * KDIM + gch * 8;
    const unsigned short* gBsrc = Yb + (size_t)(bn * BN + srow) * KDIM + gch * 8;

    const int lane = tid & 63;
    const int wv = tid >> 6;
    const int wm = wv >> 2;   // 0..1 -> A rows wm*128..
    const int wn = wv & 3;    // 0..3 -> B rows wn*64..
    const int l15 = lane & 15;
    const int kb = lane >> 4;      // 0..3 k-block
    const int sw = lane & 7;       // swizzle xor term (row&7 of the frag row)

    // Fragment LDS element offsets: row*64 + swizzled-chunk*8.
    const int aRow = (wm * 128 + l15) * 64;            // + mi*1024 + cp
    const int bRow = ABUF_E + (wn * 64 + l15) * 64;    // + ni*1024 + cp
    const int cp0 = ((kb) ^ sw) * 8;                   // kh=0 chunk
    const int cp1 = ((4 + kb) ^ sw) * 8;               // kh=1 chunk

    f32x4 acc[8][4];
#pragma unroll
    for (int i = 0; i < 8; ++i)
#pragma unroll
        for (int j = 0; j < 4; ++j) acc[i][j] = (f32x4){};

    __bf16* buf0 = lds;
    __bf16* buf1 = lds + BUF_E;

    // ---- prologue: tile 0 complete (8 loads) + tile 1's A02,B01,B23 (6 loads)
    STA(buf0, 0, 0); STA(buf0, 0, 2);
    STB(buf0, 0, 0); STB(buf0, 0, 1); STB(buf0, 0, 2); STB(buf0, 0, 3);
    STA(buf0, 0, 1); STA(buf0, 0, 3);
    STA(buf1, 1, 0); STA(buf1, 1, 2);
    STB(buf1, 1, 0); STB(buf1, 1, 1); STB(buf1, 1, 2); STB(buf1, 1, 3);
    asm volatile("s_waitcnt vmcnt(6)" ::: "memory");  // tile 0 landed; tile 1's 6 in flight
    __builtin_amdgcn_sched_barrier(0);
    __builtin_amdgcn_s_barrier();

    // ---- main: 7 full iterations + 1 last (NT=16 tiles)
#pragma unroll 1
    for (int i = 0; i < 7; ++i)
        iter8<false>(buf0, buf1, gAsrc, gBsrc, 2 * i, aRow, bRow, cp0, cp1, tid, acc);
    iter8<true>(buf0, buf1, gAsrc, gBsrc, 14, aRow, bRow, cp0, cp1, tid, acc);

    // Epilogue. C/D (16x16, m89/m91): col = lane&15, row = (lane>>4)*4 + reg.
    const int grbase = bm * BM + wm * 128 + kb * 4;
    const int gcbase = bn * BN + wn * 64 + l15;
    float sy[4];
#pragma unroll
    for (int ni = 0; ni < 4; ++ni) sy[ni] = rny[gcbase + ni * 16] * TEMP_INV;

#pragma unroll
    for (int mi = 0; mi < 8; ++mi) {
#pragma unroll
        for (int r = 0; r < 4; ++r) {
            const int grow = grbase + mi * 16 + r;
            const float rx = rnx[grow];
            float* orow = out + (size_t)grow * NDIM;
#pragma unroll
            for (int ni = 0; ni < 4; ++ni)
                orow[gcbase + ni * 16] = acc[mi][ni][r] * rx * sy[ni];
        }
    }
}

extern "C" void kernel_launch(void* const* d_in, const int* in_sizes, int n_in,
                              void* d_out, int out_size, void* d_ws, size_t ws_size,
                              hipStream_t stream) {
    const float* x = (const float*)d_in[0];
    const float* y = (const float*)d_in[1];
    float* out = (float*)d_out;

    char* ws = (char*)d_ws;
    unsigned short* Xb = (unsigned short*)ws;                              // 8 MB
    unsigned short* Yb = (unsigned short*)(ws + (size_t)MDIM * KDIM * 2);  // 8 MB
    float* rnx = (float*)(ws + (size_t)(MDIM + NDIM) * KDIM * 2);
    float* rny = rnx + MDIM;

    prep_kernel<<<dim3(MDIM / 4, 2), 256, 0, stream>>>(x, y, Xb, Yb, rnx, rny);
    gemm_cos_kernel<<<dim3(NDIM / BN, MDIM / BM), 512, 0, stream>>>(Xb, Yb, rnx, rny, out);
}